// Round 22
// baseline (110.912 us; speedup 1.0000x reference)
//
#include <hip/hip_runtime.h>

typedef __attribute__((ext_vector_type(8))) __bf16 bf16x8;
typedef __attribute__((ext_vector_type(4))) float f32x4;
typedef __attribute__((ext_vector_type(16))) float f32x16;
typedef __attribute__((ext_vector_type(4))) unsigned int u32x4;
typedef unsigned short u16;
typedef unsigned int u32;

__device__ __forceinline__ u16 f2bf(float f) {
  __bf16 h = (__bf16)f;
  return *(u16*)&h;
}
__device__ __forceinline__ float bf2f(u16 h) {
  return __uint_as_float(((u32)h) << 16);
}
__device__ __forceinline__ u32 pack2(float lo, float hi) {
  return (u32)f2bf(lo) | ((u32)f2bf(hi) << 16);
}
__device__ __forceinline__ f32x4 mfma16(bf16x8 a, bf16x8 b, f32x4 c) {
  return __builtin_amdgcn_mfma_f32_16x16x32_bf16(a, b, c, 0, 0, 0);
}
__device__ __forceinline__ f32x16 mfma32(bf16x8 a, bf16x8 b, f32x16 c) {
  return __builtin_amdgcn_mfma_f32_32x32x16_bf16(a, b, c, 0, 0, 0);
}
__device__ __forceinline__ void gl16(const void* g, void* l) {
  __builtin_amdgcn_global_load_lds(
      (const __attribute__((address_space(1))) void*)g,
      (__attribute__((address_space(3))) void*)l, 16, 0, 0);
}

#define LOG2E 1.44269504088896340736f

// ---------------- fused prep: x->bf16 (0..4095), wqkv^T (4096..4863),
//                  wproj^T (4864..5119), rel_table cvt*log2e (5120..5246) ----------
__global__ __launch_bounds__(256) void prep_all(
    const float* __restrict__ x, const float* __restrict__ w_qkv,
    const float* __restrict__ w_proj, const float* __restrict__ rel_tab,
    u16* __restrict__ xb, u16* __restrict__ wT, u16* __restrict__ wpT,
    u16* __restrict__ tabb)
{
  __shared__ float tile[32][33];
  const int b = blockIdx.x;
  const int tid = threadIdx.x;
  if (b < 4096) {
    const int i = (b * 256 + tid) * 4;
    const float4 v = *(const float4*)(x + i);
    ushort4 o; o.x = f2bf(v.x); o.y = f2bf(v.y); o.z = f2bf(v.z); o.w = f2bf(v.w);
    *(ushort4*)(xb + i) = o;
    return;
  }
  const int bp = b - 4096;
  if (bp < 1024) {
    const float* src; u16* dst; int C, c0, r0;
    if (bp < 768) { src = w_qkv; dst = wT; C = 1536; c0 = (bp % 48) * 32; r0 = (bp / 48) * 32; }
    else { const int bb = bp - 768; src = w_proj; dst = wpT; C = 512; c0 = (bb % 16) * 32; r0 = (bb / 16) * 32; }
    const int tx = tid & 31, ty = tid >> 5;
    for (int i = ty; i < 32; i += 8)
      tile[i][tx] = src[(size_t)(r0 + i) * C + c0 + tx];
    __syncthreads();
    for (int i = ty; i < 32; i += 8)
      dst[(size_t)(c0 + i) * 512 + r0 + tx] = f2bf(tile[tx][i]);
  } else {
    const int i = ((bp - 1024) * 256 + tid) * 4;
    if (i + 3 < 16131 * 8) {
      const float4 v = *(const float4*)(rel_tab + i);
      ushort4 o;
      o.x = f2bf(v.x * LOG2E); o.y = f2bf(v.y * LOG2E);
      o.z = f2bf(v.z * LOG2E); o.w = f2bf(v.w * LOG2E);
      *(ushort4*)(tabb + i) = o;
    }
  }
}

// ---------------- fused QKV GEMM: blocks 0..511 = QK-producer, 512..767 = V ------
// Q pre-scaled by 0.125*log2e (exp2 domain).
__global__ __launch_bounds__(256, 2) void gemm_qkv(
    const u16* __restrict__ xb, const u16* __restrict__ wT,
    u16* __restrict__ Qs, u16* __restrict__ Ks, u16* __restrict__ Vs)
{
  __shared__ u16 As[128][32];
  __shared__ u16 Bs[128][32];
  const int bid = blockIdx.x;
  const bool modeV = bid >= 512;
  const u16* A; const u16* Bt; int m0, n0;
  if (!modeV) {
    A = wT; Bt = xb;
    m0 = (bid >> 6) * 128; n0 = (bid & 63) * 128;
  } else {
    const int r = bid - 512;
    A = xb; Bt = wT + 1024 * 512;
    m0 = (r & 63) * 128; n0 = (r >> 6) * 128;
  }
  const int tid = threadIdx.x;
  const int w = tid >> 6, l = tid & 63;
  const int lr = l & 15, lg = l >> 4;
  const int wr = w >> 1, wc = w & 1;
  const int sl = (lr >> 1) & 3;
  const int cA = lg ^ sl;

  f32x4 acc[4][4] = {};

  for (int k0 = 0; k0 < 512; k0 += 32) {
#pragma unroll
    for (int it = 0; it < 2; ++it) {
      const int ch = it * 256 + tid;
      const int row = ch >> 2, cslot = ch & 3;
      const int csrc = cslot ^ ((row >> 1) & 3);
      gl16(A  + (size_t)(m0 + row) * 512 + k0 + csrc * 8, (u16*)As + ch * 8);
      gl16(Bt + (size_t)(n0 + row) * 512 + k0 + csrc * 8, (u16*)Bs + ch * 8);
    }
    __syncthreads();
    bf16x8 af[4], bfr[4];
#pragma unroll
    for (int mi = 0; mi < 4; ++mi)
      af[mi] = *(const bf16x8*)&As[wr * 64 + mi * 16 + lr][cA * 8];
#pragma unroll
    for (int nj = 0; nj < 4; ++nj)
      bfr[nj] = *(const bf16x8*)&Bs[wc * 64 + nj * 16 + lr][cA * 8];
#pragma unroll
    for (int mi = 0; mi < 4; ++mi)
#pragma unroll
      for (int nj = 0; nj < 4; ++nj)
        acc[mi][nj] = mfma16(af[mi], bfr[nj], acc[mi][nj]);
    __syncthreads();
  }

#pragma unroll
  for (int mi = 0; mi < 4; ++mi)
#pragma unroll
    for (int nj = 0; nj < 4; ++nj) {
      const int i0 = m0 + wr * 64 + mi * 16 + lg * 4;
      const int j  = n0 + wc * 64 + nj * 16 + lr;
      if (!modeV) {
        const int bb = j >> 10, n = j & 1023;
        const bool isQ = i0 < 512;
        const int f = isQ ? i0 : i0 - 512;
        const int h = f >> 6, d0 = f & 63;
        const float scl = isQ ? 0.125f * LOG2E : 1.0f;
        u16* dst = isQ ? Qs : Ks;
        const size_t off = ((size_t)(bb * 8 + h) << 16) +
            ((((n >> 5) * 4 + (d0 >> 4)) * 2 + ((d0 >> 3) & 1)) << 8) +
            ((n & 31) << 3) + (d0 & 7);
        ushort4 o;
        o.x = f2bf(acc[mi][nj][0] * scl); o.y = f2bf(acc[mi][nj][1] * scl);
        o.z = f2bf(acc[mi][nj][2] * scl); o.w = f2bf(acc[mi][nj][3] * scl);
        *(ushort4*)(dst + off) = o;
      } else {
        const int bb = i0 >> 10, m = i0 & 1023;
        const int h = j >> 6, d = j & 63;
        const size_t off = ((size_t)(bb * 8 + h) << 16) +
            ((((m >> 6) * 4 + ((m >> 4) & 3)) * 2 + ((m >> 2) & 1)) << 9) +
            (d << 3) + (((m >> 3) & 1) << 2);
        ushort4 o;
        o.x = f2bf(acc[mi][nj][0]); o.y = f2bf(acc[mi][nj][1]);
        o.z = f2bf(acc[mi][nj][2]); o.w = f2bf(acc[mi][nj][3]);
        *(ushort4*)(Vs + off) = o;
      }
    }
}

// ---------------- proj GEMM ----------------
__global__ __launch_bounds__(256, 2) void gemm_proj(
    const u16* __restrict__ A, const u16* __restrict__ Bt,
    float* __restrict__ fout, const float* __restrict__ bias)
{
  __shared__ u16 As[128][32];
  __shared__ u16 Bs[128][32];
  const int tid = threadIdx.x;
  const int w = tid >> 6, l = tid & 63;
  const int lr = l & 15, lg = l >> 4;
  const int wr = w >> 1, wc = w & 1;
  const int m0 = blockIdx.y * 128, n0 = blockIdx.x * 128;
  const int sl = (lr >> 1) & 3;
  const int cA = lg ^ sl;

  f32x4 acc[4][4] = {};

  for (int k0 = 0; k0 < 512; k0 += 32) {
#pragma unroll
    for (int it = 0; it < 2; ++it) {
      const int ch = it * 256 + tid;
      const int row = ch >> 2, cslot = ch & 3;
      const int csrc = cslot ^ ((row >> 1) & 3);
      gl16(A  + (size_t)(m0 + row) * 512 + k0 + csrc * 8, (u16*)As + ch * 8);
      gl16(Bt + (size_t)(n0 + row) * 512 + k0 + csrc * 8, (u16*)Bs + ch * 8);
    }
    __syncthreads();
    bf16x8 af[4], bfr[4];
#pragma unroll
    for (int mi = 0; mi < 4; ++mi)
      af[mi] = *(const bf16x8*)&As[wr * 64 + mi * 16 + lr][cA * 8];
#pragma unroll
    for (int nj = 0; nj < 4; ++nj)
      bfr[nj] = *(const bf16x8*)&Bs[wc * 64 + nj * 16 + lr][cA * 8];
#pragma unroll
    for (int mi = 0; mi < 4; ++mi)
#pragma unroll
      for (int nj = 0; nj < 4; ++nj)
        acc[mi][nj] = mfma16(af[mi], bfr[nj], acc[mi][nj]);
    __syncthreads();
  }

#pragma unroll
  for (int mi = 0; mi < 4; ++mi)
#pragma unroll
    for (int nj = 0; nj < 4; ++nj) {
      const int i0 = m0 + wr * 64 + mi * 16 + lg * 4;
      const int j  = n0 + wc * 64 + nj * 16 + lr;
      const float4 bp = *(const float4*)(bias + i0);
      float4 o;
      o.x = acc[mi][nj][0] + bp.x; o.y = acc[mi][nj][1] + bp.y;
      o.z = acc[mi][nj][2] + bp.z; o.w = acc[mi][nj][3] + bp.w;
      *(float4*)(fout + (size_t)j * 512 + i0) = o;
    }
}

// ---------------- flash attention (32x32 swapped-operand, sigma-PV, LDS table) ----
// grid 256 (1/CU), 1024 thr = 16 waves = 4 heads x 2 q-subtiles x 2 KV-halves.
// exp2 domain (Q,bias pre-scaled by log2e) -> v_exp without the v_mul.
// Per-u restructure: V loads for this u issued BEFORE the QK MFMA + exp chain
// (~600cy cover), PV consumes ready registers. +16 VGPR, fits the 128 cap.
__global__ __launch_bounds__(1024) void flash_attn(
    const u16* __restrict__ Qs, const u16* __restrict__ Ks,
    const u16* __restrict__ Vs, const int* __restrict__ ids_keep,
    const u16* __restrict__ tab_bf,
    u16* __restrict__ attn_out)
{
  __shared__ union {
    u16 tabL[2][16129 * 2];    // [head-pair][idx*2 + hlow], 4B stride, 129 KB
    float comb[8][33][64];     // epilogue KV-half combine
  } sm;
  __shared__ int bofs[1024];   // (8064 - code[m]) * 4  (byte offset)

  const int bid = blockIdx.x;
  const int bb = bid & 7;
  const int r2 = bid >> 3;
  const int hp = r2 & 1;
  const int g64 = r2 >> 1;
  const int tid = threadIdx.x;
  const int wv = tid >> 6;          // 0..15
  const int hloc = wv & 3;
  const int qs = (wv >> 2) & 1;
  const int kvh = wv >> 3;          // KV half
  const int l = tid & 63, l31 = l & 31, hi5 = l >> 5;
  const int h = hp * 4 + hloc;
  const int t0 = kvh * 8;

  for (int e = tid; e < 16129 * 2; e += 1024) {
    const int hi = e >= 16129;
    const int ee = hi ? e - 16129 : e;
    *(u32*)&sm.tabL[hi][ee * 2] =
        *(const u32*)(tab_bf + (size_t)ee * 8 + hp * 4 + hi * 2);
  }
  {
    const int id = ids_keep[bb * 1024 + tid];
    bofs[tid] = (8064 - ((id >> 6) * 127 + (id & 63))) * 4;
  }

  const int nloc = g64 * 64 + qs * 32 + l31;
  const int idn = ids_keep[bb * 1024 + nloc];
  const int base = ((idn >> 6) * 127 + (idn & 63)) * 4 + (hloc & 1) * 2;  // bytes

  const size_t hb = (size_t)(bb * 8 + h) << 16;
  const int g32 = g64 * 2 + qs;

  f32x16 acc0 = {}, acc1 = {};
  float lsum = 0.f;

  bf16x8 qf[4];
#pragma unroll
  for (int dch = 0; dch < 4; ++dch)
    qf[dch] = *(const bf16x8*)(Qs + hb + (size_t)(((g32 * 4 + dch) * 2 + hi5) * 256 + l31 * 8));

  __syncthreads();   // tabL + bofs ready; main loop barrier-free

  const char* tb = (const char*)sm.tabL[hloc >> 1];

  for (int t = t0; t < t0 + 8; ++t) {
#pragma unroll
    for (int u = 0; u < 2; ++u) {
      // K for this u + V for this u's two cp slices: issued together, consumed
      // ~600cy later (V) after the MFMA+exp chain.
      bf16x8 kc[4], vc[2][2];
#pragma unroll
      for (int dch = 0; dch < 4; ++dch)
        kc[dch] = *(const bf16x8*)(Ks + hb +
            (size_t)((((2 * t + u) * 4 + dch) * 2 + hi5) * 256 + l31 * 8));
#pragma unroll
      for (int cc = 0; cc < 2; ++cc)
#pragma unroll
        for (int dc = 0; dc < 2; ++dc)
          vc[cc][dc] = *(const bf16x8*)(Vs + hb +
              (size_t)(((t * 4 + 2 * u + cc) * 2 + hi5) * 512 + (dc * 32 + l31) * 8));

      f32x16 s = {};
      s = mfma32(kc[0], qf[0], s);
      s = mfma32(kc[1], qf[1], s);
      s = mfma32(kc[2], qf[2], s);
      s = mfma32(kc[3], qf[3], s);

      u32 pk[4][2];
#pragma unroll
      for (int a = 0; a < 4; ++a) {
        // m = 32u + 8a + 4*hi5 + r
        const int4 bo = *(const int4*)&bofs[t * 64 + u * 32 + a * 8 + hi5 * 4];
        const float b0 = bf2f(*(const u16*)(tb + base + bo.x));
        const float b1 = bf2f(*(const u16*)(tb + base + bo.y));
        const float b2 = bf2f(*(const u16*)(tb + base + bo.z));
        const float b3 = bf2f(*(const u16*)(tb + base + bo.w));
        float p0 = exp2f(s[a * 4 + 0] + b0);
        float p1 = exp2f(s[a * 4 + 1] + b1);
        float p2 = exp2f(s[a * 4 + 2] + b2);
        float p3 = exp2f(s[a * 4 + 3] + b3);
        lsum += (p0 + p1) + (p2 + p3);
        pk[a][0] = pack2(p0, p1);
        pk[a][1] = pack2(p2, p3);
      }

#pragma unroll
      for (int cc = 0; cc < 2; ++cc) {
        union { u32x4 u4; bf16x8 v; } pb;
        pb.u4 = (u32x4){pk[2 * cc][0], pk[2 * cc][1],
                        pk[2 * cc + 1][0], pk[2 * cc + 1][1]};
        acc0 = mfma32(vc[cc][0], pb.v, acc0);
        acc1 = mfma32(vc[cc][1], pb.v, acc1);
      }
    }
  }

  lsum += __shfl_xor(lsum, 32);

  // in-block KV-half combine through the (now dead) table LDS
  __syncthreads();
  const int slot = wv & 7;
  if (kvh == 1) {
#pragma unroll
    for (int r = 0; r < 16; ++r) sm.comb[slot][r][l]      = acc0[r];
#pragma unroll
    for (int r = 0; r < 16; ++r) sm.comb[slot][16 + r][l] = acc1[r];
    sm.comb[slot][32][l] = lsum;
  }
  __syncthreads();
  if (kvh == 0) {
    const float inv = 1.0f / (lsum + sm.comb[slot][32][l]);
    const int nglob = bb * 1024 + nloc;
#pragma unroll
    for (int dc = 0; dc < 2; ++dc) {
      const f32x16& av = dc ? acc1 : acc0;
#pragma unroll
      for (int rq = 0; rq < 4; ++rq) {
        const int d = dc * 32 + rq * 8 + hi5 * 4;
        ushort4 o;
        o.x = f2bf((av[rq * 4 + 0] + sm.comb[slot][dc * 16 + rq * 4 + 0][l]) * inv);
        o.y = f2bf((av[rq * 4 + 1] + sm.comb[slot][dc * 16 + rq * 4 + 1][l]) * inv);
        o.z = f2bf((av[rq * 4 + 2] + sm.comb[slot][dc * 16 + rq * 4 + 2][l]) * inv);
        o.w = f2bf((av[rq * 4 + 3] + sm.comb[slot][dc * 16 + rq * 4 + 3][l]) * inv);
        *(ushort4*)(attn_out + (size_t)nglob * 512 + h * 64 + d) = o;
      }
    }
  }
}

// ---------------- launch ----------------
extern "C" void kernel_launch(void* const* d_in, const int* in_sizes, int n_in,
                              void* d_out, int out_size, void* d_ws, size_t ws_size,
                              hipStream_t stream) {
  const float* x        = (const float*)d_in[0];
  const int*   ids      = (const int*)d_in[1];
  const float* w_qkv    = (const float*)d_in[2];
  const float* w_proj   = (const float*)d_in[3];
  const float* b_proj   = (const float*)d_in[4];
  const float* rel_tab  = (const float*)d_in[5];
  float* out = (float*)d_out;

  char* ws = (char*)d_ws;
  u16* xb   = (u16*)(ws);              // 8192x512 bf16; later reused as attn_out
  u16* wT   = (u16*)(ws + 8388608);    // 1536x512 bf16
  u16* wpT  = (u16*)(ws + 9961472);    // 512x512 bf16
  u16* Qsw  = (u16*)(ws + 10485760);   // swizzled Q, pre-scaled 0.125*log2e (8MB)
  u16* Ksw  = (u16*)(ws + 18874368);   // swizzled K (8MB)
  u16* Vsw  = (u16*)(ws + 27262976);   // sigma-swizzled V (8MB)
  u16* tabb = (u16*)(ws + 35651584);   // bf16 rel_table*log2e [16131][8] (258KB)
  u16* attn = xb;

  prep_all<<<5247, 256, 0, stream>>>(x, w_qkv, w_proj, rel_tab, xb, wT, wpT, tabb);
  gemm_qkv<<<768, 256, 0, stream>>>(xb, wT, Qsw, Ksw, Vsw);
  flash_attn<<<dim3(256), 1024, 0, stream>>>(Qsw, Ksw, Vsw, ids, tabb, attn);
  gemm_proj<<<dim3(64, 4), 256, 0, stream>>>(wpT, attn, out, b_proj);
}

// Round 23
// 96.270 us; speedup vs baseline: 1.1521x; 1.1521x over previous
//
#include <hip/hip_runtime.h>

typedef __attribute__((ext_vector_type(8))) __bf16 bf16x8;
typedef __attribute__((ext_vector_type(4))) float f32x4;
typedef __attribute__((ext_vector_type(16))) float f32x16;
typedef __attribute__((ext_vector_type(4))) unsigned int u32x4;
typedef unsigned short u16;
typedef unsigned int u32;

__device__ __forceinline__ u16 f2bf(float f) {
  __bf16 h = (__bf16)f;
  return *(u16*)&h;
}
__device__ __forceinline__ float bf2f(u16 h) {
  return __uint_as_float(((u32)h) << 16);
}
__device__ __forceinline__ u32 pack2(float lo, float hi) {
  return (u32)f2bf(lo) | ((u32)f2bf(hi) << 16);
}
__device__ __forceinline__ f32x4 mfma16(bf16x8 a, bf16x8 b, f32x4 c) {
  return __builtin_amdgcn_mfma_f32_16x16x32_bf16(a, b, c, 0, 0, 0);
}
__device__ __forceinline__ f32x16 mfma32(bf16x8 a, bf16x8 b, f32x16 c) {
  return __builtin_amdgcn_mfma_f32_32x32x16_bf16(a, b, c, 0, 0, 0);
}
__device__ __forceinline__ void gl16(const void* g, void* l) {
  __builtin_amdgcn_global_load_lds(
      (const __attribute__((address_space(1))) void*)g,
      (__attribute__((address_space(3))) void*)l, 16, 0, 0);
}

#define LOG2E 1.44269504088896340736f

// ---------------- fused prep: x->bf16 (0..4095), wqkv^T (4096..4863),
//                  wproj^T (4864..5119), rel_table cvt*log2e (5120..5246) ----------
__global__ __launch_bounds__(256) void prep_all(
    const float* __restrict__ x, const float* __restrict__ w_qkv,
    const float* __restrict__ w_proj, const float* __restrict__ rel_tab,
    u16* __restrict__ xb, u16* __restrict__ wT, u16* __restrict__ wpT,
    u16* __restrict__ tabb)
{
  __shared__ float tile[32][33];
  const int b = blockIdx.x;
  const int tid = threadIdx.x;
  if (b < 4096) {
    const int i = (b * 256 + tid) * 4;
    const float4 v = *(const float4*)(x + i);
    ushort4 o; o.x = f2bf(v.x); o.y = f2bf(v.y); o.z = f2bf(v.z); o.w = f2bf(v.w);
    *(ushort4*)(xb + i) = o;
    return;
  }
  const int bp = b - 4096;
  if (bp < 1024) {
    const float* src; u16* dst; int C, c0, r0;
    if (bp < 768) { src = w_qkv; dst = wT; C = 1536; c0 = (bp % 48) * 32; r0 = (bp / 48) * 32; }
    else { const int bb = bp - 768; src = w_proj; dst = wpT; C = 512; c0 = (bb % 16) * 32; r0 = (bb / 16) * 32; }
    const int tx = tid & 31, ty = tid >> 5;
    for (int i = ty; i < 32; i += 8)
      tile[i][tx] = src[(size_t)(r0 + i) * C + c0 + tx];
    __syncthreads();
    for (int i = ty; i < 32; i += 8)
      dst[(size_t)(c0 + i) * 512 + r0 + tx] = f2bf(tile[tx][i]);
  } else {
    const int i = ((bp - 1024) * 256 + tid) * 4;
    if (i + 3 < 16131 * 8) {
      const float4 v = *(const float4*)(rel_tab + i);
      ushort4 o;
      o.x = f2bf(v.x * LOG2E); o.y = f2bf(v.y * LOG2E);
      o.z = f2bf(v.z * LOG2E); o.w = f2bf(v.w * LOG2E);
      *(ushort4*)(tabb + i) = o;
    }
  }
}

// ---------------- fused QKV GEMM: blocks 0..511 = QK-producer, 512..767 = V ------
// Q pre-scaled by 0.125*log2e (exp2 domain).
__global__ __launch_bounds__(256, 2) void gemm_qkv(
    const u16* __restrict__ xb, const u16* __restrict__ wT,
    u16* __restrict__ Qs, u16* __restrict__ Ks, u16* __restrict__ Vs)
{
  __shared__ u16 As[128][32];
  __shared__ u16 Bs[128][32];
  const int bid = blockIdx.x;
  const bool modeV = bid >= 512;
  const u16* A; const u16* Bt; int m0, n0;
  if (!modeV) {
    A = wT; Bt = xb;
    m0 = (bid >> 6) * 128; n0 = (bid & 63) * 128;
  } else {
    const int r = bid - 512;
    A = xb; Bt = wT + 1024 * 512;
    m0 = (r & 63) * 128; n0 = (r >> 6) * 128;
  }
  const int tid = threadIdx.x;
  const int w = tid >> 6, l = tid & 63;
  const int lr = l & 15, lg = l >> 4;
  const int wr = w >> 1, wc = w & 1;
  const int sl = (lr >> 1) & 3;
  const int cA = lg ^ sl;

  f32x4 acc[4][4] = {};

  for (int k0 = 0; k0 < 512; k0 += 32) {
#pragma unroll
    for (int it = 0; it < 2; ++it) {
      const int ch = it * 256 + tid;
      const int row = ch >> 2, cslot = ch & 3;
      const int csrc = cslot ^ ((row >> 1) & 3);
      gl16(A  + (size_t)(m0 + row) * 512 + k0 + csrc * 8, (u16*)As + ch * 8);
      gl16(Bt + (size_t)(n0 + row) * 512 + k0 + csrc * 8, (u16*)Bs + ch * 8);
    }
    __syncthreads();
    bf16x8 af[4], bfr[4];
#pragma unroll
    for (int mi = 0; mi < 4; ++mi)
      af[mi] = *(const bf16x8*)&As[wr * 64 + mi * 16 + lr][cA * 8];
#pragma unroll
    for (int nj = 0; nj < 4; ++nj)
      bfr[nj] = *(const bf16x8*)&Bs[wc * 64 + nj * 16 + lr][cA * 8];
#pragma unroll
    for (int mi = 0; mi < 4; ++mi)
#pragma unroll
      for (int nj = 0; nj < 4; ++nj)
        acc[mi][nj] = mfma16(af[mi], bfr[nj], acc[mi][nj]);
    __syncthreads();
  }

#pragma unroll
  for (int mi = 0; mi < 4; ++mi)
#pragma unroll
    for (int nj = 0; nj < 4; ++nj) {
      const int i0 = m0 + wr * 64 + mi * 16 + lg * 4;
      const int j  = n0 + wc * 64 + nj * 16 + lr;
      if (!modeV) {
        const int bb = j >> 10, n = j & 1023;
        const bool isQ = i0 < 512;
        const int f = isQ ? i0 : i0 - 512;
        const int h = f >> 6, d0 = f & 63;
        const float scl = isQ ? 0.125f * LOG2E : 1.0f;
        u16* dst = isQ ? Qs : Ks;
        const size_t off = ((size_t)(bb * 8 + h) << 16) +
            ((((n >> 5) * 4 + (d0 >> 4)) * 2 + ((d0 >> 3) & 1)) << 8) +
            ((n & 31) << 3) + (d0 & 7);
        ushort4 o;
        o.x = f2bf(acc[mi][nj][0] * scl); o.y = f2bf(acc[mi][nj][1] * scl);
        o.z = f2bf(acc[mi][nj][2] * scl); o.w = f2bf(acc[mi][nj][3] * scl);
        *(ushort4*)(dst + off) = o;
      } else {
        const int bb = i0 >> 10, m = i0 & 1023;
        const int h = j >> 6, d = j & 63;
        const size_t off = ((size_t)(bb * 8 + h) << 16) +
            ((((m >> 6) * 4 + ((m >> 4) & 3)) * 2 + ((m >> 2) & 1)) << 9) +
            (d << 3) + (((m >> 3) & 1) << 2);
        ushort4 o;
        o.x = f2bf(acc[mi][nj][0]); o.y = f2bf(acc[mi][nj][1]);
        o.z = f2bf(acc[mi][nj][2]); o.w = f2bf(acc[mi][nj][3]);
        *(ushort4*)(Vs + off) = o;
      }
    }
}

// ---------------- proj GEMM ----------------
__global__ __launch_bounds__(256, 2) void gemm_proj(
    const u16* __restrict__ A, const u16* __restrict__ Bt,
    float* __restrict__ fout, const float* __restrict__ bias)
{
  __shared__ u16 As[128][32];
  __shared__ u16 Bs[128][32];
  const int tid = threadIdx.x;
  const int w = tid >> 6, l = tid & 63;
  const int lr = l & 15, lg = l >> 4;
  const int wr = w >> 1, wc = w & 1;
  const int m0 = blockIdx.y * 128, n0 = blockIdx.x * 128;
  const int sl = (lr >> 1) & 3;
  const int cA = lg ^ sl;

  f32x4 acc[4][4] = {};

  for (int k0 = 0; k0 < 512; k0 += 32) {
#pragma unroll
    for (int it = 0; it < 2; ++it) {
      const int ch = it * 256 + tid;
      const int row = ch >> 2, cslot = ch & 3;
      const int csrc = cslot ^ ((row >> 1) & 3);
      gl16(A  + (size_t)(m0 + row) * 512 + k0 + csrc * 8, (u16*)As + ch * 8);
      gl16(Bt + (size_t)(n0 + row) * 512 + k0 + csrc * 8, (u16*)Bs + ch * 8);
    }
    __syncthreads();
    bf16x8 af[4], bfr[4];
#pragma unroll
    for (int mi = 0; mi < 4; ++mi)
      af[mi] = *(const bf16x8*)&As[wr * 64 + mi * 16 + lr][cA * 8];
#pragma unroll
    for (int nj = 0; nj < 4; ++nj)
      bfr[nj] = *(const bf16x8*)&Bs[wc * 64 + nj * 16 + lr][cA * 8];
#pragma unroll
    for (int mi = 0; mi < 4; ++mi)
#pragma unroll
      for (int nj = 0; nj < 4; ++nj)
        acc[mi][nj] = mfma16(af[mi], bfr[nj], acc[mi][nj]);
    __syncthreads();
  }

#pragma unroll
  for (int mi = 0; mi < 4; ++mi)
#pragma unroll
    for (int nj = 0; nj < 4; ++nj) {
      const int i0 = m0 + wr * 64 + mi * 16 + lg * 4;
      const int j  = n0 + wc * 64 + nj * 16 + lr;
      const float4 bp = *(const float4*)(bias + i0);
      float4 o;
      o.x = acc[mi][nj][0] + bp.x; o.y = acc[mi][nj][1] + bp.y;
      o.z = acc[mi][nj][2] + bp.z; o.w = acc[mi][nj][3] + bp.w;
      *(float4*)(fout + (size_t)j * 512 + i0) = o;
    }
}

// ---------------- flash attention (32x32 swapped-operand, sigma-PV, LDS table) ----
// grid 256 (1/CU), 1024 thr = 16 waves = 4 heads x 2 q-subtiles x 2 KV-halves.
// Round-20 register shape (V loaded per-cp in PV loop: NO added live state) +
// exp2 domain (Q,bias pre-scaled by log2e -> v_exp without v_mul) +
// 4B-stride bank-split table.
__global__ __launch_bounds__(1024) void flash_attn(
    const u16* __restrict__ Qs, const u16* __restrict__ Ks,
    const u16* __restrict__ Vs, const int* __restrict__ ids_keep,
    const u16* __restrict__ tab_bf,
    u16* __restrict__ attn_out)
{
  __shared__ union {
    u16 tabL[2][16129 * 2];    // [head-pair][idx*2 + hlow], 4B stride, 129 KB
    float comb[8][33][64];     // epilogue KV-half combine
  } sm;
  __shared__ int bofs[1024];   // (8064 - code[m]) * 4  (byte offset)

  const int bid = blockIdx.x;
  const int bb = bid & 7;
  const int r2 = bid >> 3;
  const int hp = r2 & 1;
  const int g64 = r2 >> 1;
  const int tid = threadIdx.x;
  const int wv = tid >> 6;          // 0..15
  const int hloc = wv & 3;
  const int qs = (wv >> 2) & 1;
  const int kvh = wv >> 3;          // KV half
  const int l = tid & 63, l31 = l & 31, hi5 = l >> 5;
  const int h = hp * 4 + hloc;
  const int t0 = kvh * 8;

  for (int e = tid; e < 16129 * 2; e += 1024) {
    const int hi = e >= 16129;
    const int ee = hi ? e - 16129 : e;
    *(u32*)&sm.tabL[hi][ee * 2] =
        *(const u32*)(tab_bf + (size_t)ee * 8 + hp * 4 + hi * 2);
  }
  {
    const int id = ids_keep[bb * 1024 + tid];
    bofs[tid] = (8064 - ((id >> 6) * 127 + (id & 63))) * 4;
  }

  const int nloc = g64 * 64 + qs * 32 + l31;
  const int idn = ids_keep[bb * 1024 + nloc];
  const int base = ((idn >> 6) * 127 + (idn & 63)) * 4 + (hloc & 1) * 2;  // bytes

  const size_t hb = (size_t)(bb * 8 + h) << 16;
  const int g32 = g64 * 2 + qs;

  f32x16 acc0 = {}, acc1 = {};
  float lsum = 0.f;

  bf16x8 qf[4];
#pragma unroll
  for (int dch = 0; dch < 4; ++dch)
    qf[dch] = *(const bf16x8*)(Qs + hb + (size_t)(((g32 * 4 + dch) * 2 + hi5) * 256 + l31 * 8));

  __syncthreads();   // tabL + bofs ready; main loop barrier-free

  const char* tb = (const char*)sm.tabL[hloc >> 1];

  for (int t = t0; t < t0 + 8; ++t) {
    u32 pk[2][4][2];
#pragma unroll
    for (int u = 0; u < 2; ++u) {
      bf16x8 kc[4];
#pragma unroll
      for (int dch = 0; dch < 4; ++dch)
        kc[dch] = *(const bf16x8*)(Ks + hb +
            (size_t)((((2 * t + u) * 4 + dch) * 2 + hi5) * 256 + l31 * 8));
      f32x16 s = {};
      s = mfma32(kc[0], qf[0], s);
      s = mfma32(kc[1], qf[1], s);
      s = mfma32(kc[2], qf[2], s);
      s = mfma32(kc[3], qf[3], s);
#pragma unroll
      for (int a = 0; a < 4; ++a) {
        // m = 32u + 8a + 4*hi5 + r
        const int4 bo = *(const int4*)&bofs[t * 64 + u * 32 + a * 8 + hi5 * 4];
        const float b0 = bf2f(*(const u16*)(tb + base + bo.x));
        const float b1 = bf2f(*(const u16*)(tb + base + bo.y));
        const float b2 = bf2f(*(const u16*)(tb + base + bo.z));
        const float b3 = bf2f(*(const u16*)(tb + base + bo.w));
        float p0 = exp2f(s[a * 4 + 0] + b0);
        float p1 = exp2f(s[a * 4 + 1] + b1);
        float p2 = exp2f(s[a * 4 + 2] + b2);
        float p3 = exp2f(s[a * 4 + 3] + b3);
        lsum += (p0 + p1) + (p2 + p3);
        pk[u][a][0] = pack2(p0, p1);
        pk[u][a][1] = pack2(p2, p3);
      }
    }

#pragma unroll
    for (int cp = 0; cp < 4; ++cp) {
      bf16x8 vc[2];
#pragma unroll
      for (int dc = 0; dc < 2; ++dc)
        vc[dc] = *(const bf16x8*)(Vs + hb +
            (size_t)(((t * 4 + cp) * 2 + hi5) * 512 + (dc * 32 + l31) * 8));
      const int u = cp >> 1, cc = cp & 1;
      union { u32x4 u4; bf16x8 v; } pb;
      pb.u4 = (u32x4){pk[u][2 * cc][0], pk[u][2 * cc][1],
                      pk[u][2 * cc + 1][0], pk[u][2 * cc + 1][1]};
      acc0 = mfma32(vc[0], pb.v, acc0);
      acc1 = mfma32(vc[1], pb.v, acc1);
    }
  }

  lsum += __shfl_xor(lsum, 32);

  // in-block KV-half combine through the (now dead) table LDS
  __syncthreads();
  const int slot = wv & 7;
  if (kvh == 1) {
#pragma unroll
    for (int r = 0; r < 16; ++r) sm.comb[slot][r][l]      = acc0[r];
#pragma unroll
    for (int r = 0; r < 16; ++r) sm.comb[slot][16 + r][l] = acc1[r];
    sm.comb[slot][32][l] = lsum;
  }
  __syncthreads();
  if (kvh == 0) {
    const float inv = 1.0f / (lsum + sm.comb[slot][32][l]);
    const int nglob = bb * 1024 + nloc;
#pragma unroll
    for (int dc = 0; dc < 2; ++dc) {
      const f32x16& av = dc ? acc1 : acc0;
#pragma unroll
      for (int rq = 0; rq < 4; ++rq) {
        const int d = dc * 32 + rq * 8 + hi5 * 4;
        ushort4 o;
        o.x = f2bf((av[rq * 4 + 0] + sm.comb[slot][dc * 16 + rq * 4 + 0][l]) * inv);
        o.y = f2bf((av[rq * 4 + 1] + sm.comb[slot][dc * 16 + rq * 4 + 1][l]) * inv);
        o.z = f2bf((av[rq * 4 + 2] + sm.comb[slot][dc * 16 + rq * 4 + 2][l]) * inv);
        o.w = f2bf((av[rq * 4 + 3] + sm.comb[slot][dc * 16 + rq * 4 + 3][l]) * inv);
        *(ushort4*)(attn_out + (size_t)nglob * 512 + h * 64 + d) = o;
      }
    }
  }
}

// ---------------- launch ----------------
extern "C" void kernel_launch(void* const* d_in, const int* in_sizes, int n_in,
                              void* d_out, int out_size, void* d_ws, size_t ws_size,
                              hipStream_t stream) {
  const float* x        = (const float*)d_in[0];
  const int*   ids      = (const int*)d_in[1];
  const float* w_qkv    = (const float*)d_in[2];
  const float* w_proj   = (const float*)d_in[3];
  const float* b_proj   = (const float*)d_in[4];
  const float* rel_tab  = (const float*)d_in[5];
  float* out = (float*)d_out;

  char* ws = (char*)d_ws;
  u16* xb   = (u16*)(ws);              // 8192x512 bf16; later reused as attn_out
  u16* wT   = (u16*)(ws + 8388608);    // 1536x512 bf16
  u16* wpT  = (u16*)(ws + 9961472);    // 512x512 bf16
  u16* Qsw  = (u16*)(ws + 10485760);   // swizzled Q, pre-scaled 0.125*log2e (8MB)
  u16* Ksw  = (u16*)(ws + 18874368);   // swizzled K (8MB)
  u16* Vsw  = (u16*)(ws + 27262976);   // sigma-swizzled V (8MB)
  u16* tabb = (u16*)(ws + 35651584);   // bf16 rel_table*log2e [16131][8] (258KB)
  u16* attn = xb;

  prep_all<<<5247, 256, 0, stream>>>(x, w_qkv, w_proj, rel_tab, xb, wT, wpT, tabb);
  gemm_qkv<<<768, 256, 0, stream>>>(xb, wT, Qsw, Ksw, Vsw);
  flash_attn<<<dim3(256), 1024, 0, stream>>>(Qsw, Ksw, Vsw, ids, tabb, attn);
  gemm_proj<<<dim3(64, 4), 256, 0, stream>>>(wpT, attn, out, b_proj);
}

// Round 24
// 90.019 us; speedup vs baseline: 1.2321x; 1.0694x over previous
//
#include <hip/hip_runtime.h>

typedef __attribute__((ext_vector_type(8))) __bf16 bf16x8;
typedef __attribute__((ext_vector_type(4))) float f32x4;
typedef __attribute__((ext_vector_type(16))) float f32x16;
typedef __attribute__((ext_vector_type(4))) unsigned int u32x4;
typedef unsigned short u16;
typedef unsigned int u32;

__device__ __forceinline__ u16 f2bf(float f) {
  __bf16 h = (__bf16)f;
  return *(u16*)&h;
}
__device__ __forceinline__ float bf2f(u16 h) {
  return __uint_as_float(((u32)h) << 16);
}
__device__ __forceinline__ u32 pack2(float lo, float hi) {
  return (u32)f2bf(lo) | ((u32)f2bf(hi) << 16);
}
__device__ __forceinline__ f32x4 mfma16(bf16x8 a, bf16x8 b, f32x4 c) {
  return __builtin_amdgcn_mfma_f32_16x16x32_bf16(a, b, c, 0, 0, 0);
}
__device__ __forceinline__ f32x16 mfma32(bf16x8 a, bf16x8 b, f32x16 c) {
  return __builtin_amdgcn_mfma_f32_32x32x16_bf16(a, b, c, 0, 0, 0);
}
__device__ __forceinline__ void gl16(const void* g, void* l) {
  __builtin_amdgcn_global_load_lds(
      (const __attribute__((address_space(1))) void*)g,
      (__attribute__((address_space(3))) void*)l, 16, 0, 0);
}

#define LOG2E 1.44269504088896340736f

// ---------------- fused prep: x->bf16 (0..4095), wqkv^T (4096..4863),
//                  wproj^T (4864..5119), rel_table cvt*log2e (5120..5246) ----------
__global__ __launch_bounds__(256) void prep_all(
    const float* __restrict__ x, const float* __restrict__ w_qkv,
    const float* __restrict__ w_proj, const float* __restrict__ rel_tab,
    u16* __restrict__ xb, u16* __restrict__ wT, u16* __restrict__ wpT,
    u16* __restrict__ tabb)
{
  __shared__ float tile[32][33];
  const int b = blockIdx.x;
  const int tid = threadIdx.x;
  if (b < 4096) {
    const int i = (b * 256 + tid) * 4;
    const float4 v = *(const float4*)(x + i);
    ushort4 o; o.x = f2bf(v.x); o.y = f2bf(v.y); o.z = f2bf(v.z); o.w = f2bf(v.w);
    *(ushort4*)(xb + i) = o;
    return;
  }
  const int bp = b - 4096;
  if (bp < 1024) {
    const float* src; u16* dst; int C, c0, r0;
    if (bp < 768) { src = w_qkv; dst = wT; C = 1536; c0 = (bp % 48) * 32; r0 = (bp / 48) * 32; }
    else { const int bb = bp - 768; src = w_proj; dst = wpT; C = 512; c0 = (bb % 16) * 32; r0 = (bb / 16) * 32; }
    const int tx = tid & 31, ty = tid >> 5;
    for (int i = ty; i < 32; i += 8)
      tile[i][tx] = src[(size_t)(r0 + i) * C + c0 + tx];
    __syncthreads();
    for (int i = ty; i < 32; i += 8)
      dst[(size_t)(c0 + i) * 512 + r0 + tx] = f2bf(tile[tx][i]);
  } else {
    const int i = ((bp - 1024) * 256 + tid) * 4;
    if (i + 3 < 16131 * 8) {
      const float4 v = *(const float4*)(rel_tab + i);
      ushort4 o;
      o.x = f2bf(v.x * LOG2E); o.y = f2bf(v.y * LOG2E);
      o.z = f2bf(v.z * LOG2E); o.w = f2bf(v.w * LOG2E);
      *(ushort4*)(tabb + i) = o;
    }
  }
}

// ---------------- fused QKV GEMM: blocks 0..511 = QK-producer, 512..767 = V ------
// Q pre-scaled by 0.125*log2e (exp2 domain).
__global__ __launch_bounds__(256, 2) void gemm_qkv(
    const u16* __restrict__ xb, const u16* __restrict__ wT,
    u16* __restrict__ Qs, u16* __restrict__ Ks, u16* __restrict__ Vs)
{
  __shared__ u16 As[128][32];
  __shared__ u16 Bs[128][32];
  const int bid = blockIdx.x;
  const bool modeV = bid >= 512;
  const u16* A; const u16* Bt; int m0, n0;
  if (!modeV) {
    A = wT; Bt = xb;
    m0 = (bid >> 6) * 128; n0 = (bid & 63) * 128;
  } else {
    const int r = bid - 512;
    A = xb; Bt = wT + 1024 * 512;
    m0 = (r & 63) * 128; n0 = (r >> 6) * 128;
  }
  const int tid = threadIdx.x;
  const int w = tid >> 6, l = tid & 63;
  const int lr = l & 15, lg = l >> 4;
  const int wr = w >> 1, wc = w & 1;
  const int sl = (lr >> 1) & 3;
  const int cA = lg ^ sl;

  f32x4 acc[4][4] = {};

  for (int k0 = 0; k0 < 512; k0 += 32) {
#pragma unroll
    for (int it = 0; it < 2; ++it) {
      const int ch = it * 256 + tid;
      const int row = ch >> 2, cslot = ch & 3;
      const int csrc = cslot ^ ((row >> 1) & 3);
      gl16(A  + (size_t)(m0 + row) * 512 + k0 + csrc * 8, (u16*)As + ch * 8);
      gl16(Bt + (size_t)(n0 + row) * 512 + k0 + csrc * 8, (u16*)Bs + ch * 8);
    }
    __syncthreads();
    bf16x8 af[4], bfr[4];
#pragma unroll
    for (int mi = 0; mi < 4; ++mi)
      af[mi] = *(const bf16x8*)&As[wr * 64 + mi * 16 + lr][cA * 8];
#pragma unroll
    for (int nj = 0; nj < 4; ++nj)
      bfr[nj] = *(const bf16x8*)&Bs[wc * 64 + nj * 16 + lr][cA * 8];
#pragma unroll
    for (int mi = 0; mi < 4; ++mi)
#pragma unroll
      for (int nj = 0; nj < 4; ++nj)
        acc[mi][nj] = mfma16(af[mi], bfr[nj], acc[mi][nj]);
    __syncthreads();
  }

#pragma unroll
  for (int mi = 0; mi < 4; ++mi)
#pragma unroll
    for (int nj = 0; nj < 4; ++nj) {
      const int i0 = m0 + wr * 64 + mi * 16 + lg * 4;
      const int j  = n0 + wc * 64 + nj * 16 + lr;
      if (!modeV) {
        const int bb = j >> 10, n = j & 1023;
        const bool isQ = i0 < 512;
        const int f = isQ ? i0 : i0 - 512;
        const int h = f >> 6, d0 = f & 63;
        const float scl = isQ ? 0.125f * LOG2E : 1.0f;
        u16* dst = isQ ? Qs : Ks;
        const size_t off = ((size_t)(bb * 8 + h) << 16) +
            ((((n >> 5) * 4 + (d0 >> 4)) * 2 + ((d0 >> 3) & 1)) << 8) +
            ((n & 31) << 3) + (d0 & 7);
        ushort4 o;
        o.x = f2bf(acc[mi][nj][0] * scl); o.y = f2bf(acc[mi][nj][1] * scl);
        o.z = f2bf(acc[mi][nj][2] * scl); o.w = f2bf(acc[mi][nj][3] * scl);
        *(ushort4*)(dst + off) = o;
      } else {
        const int bb = i0 >> 10, m = i0 & 1023;
        const int h = j >> 6, d = j & 63;
        const size_t off = ((size_t)(bb * 8 + h) << 16) +
            ((((m >> 6) * 4 + ((m >> 4) & 3)) * 2 + ((m >> 2) & 1)) << 9) +
            (d << 3) + (((m >> 3) & 1) << 2);
        ushort4 o;
        o.x = f2bf(acc[mi][nj][0]); o.y = f2bf(acc[mi][nj][1]);
        o.z = f2bf(acc[mi][nj][2]); o.w = f2bf(acc[mi][nj][3]);
        *(ushort4*)(Vs + off) = o;
      }
    }
}

// ---------------- proj GEMM ----------------
__global__ __launch_bounds__(256, 2) void gemm_proj(
    const u16* __restrict__ A, const u16* __restrict__ Bt,
    float* __restrict__ fout, const float* __restrict__ bias)
{
  __shared__ u16 As[128][32];
  __shared__ u16 Bs[128][32];
  const int tid = threadIdx.x;
  const int w = tid >> 6, l = tid & 63;
  const int lr = l & 15, lg = l >> 4;
  const int wr = w >> 1, wc = w & 1;
  const int m0 = blockIdx.y * 128, n0 = blockIdx.x * 128;
  const int sl = (lr >> 1) & 3;
  const int cA = lg ^ sl;

  f32x4 acc[4][4] = {};

  for (int k0 = 0; k0 < 512; k0 += 32) {
#pragma unroll
    for (int it = 0; it < 2; ++it) {
      const int ch = it * 256 + tid;
      const int row = ch >> 2, cslot = ch & 3;
      const int csrc = cslot ^ ((row >> 1) & 3);
      gl16(A  + (size_t)(m0 + row) * 512 + k0 + csrc * 8, (u16*)As + ch * 8);
      gl16(Bt + (size_t)(n0 + row) * 512 + k0 + csrc * 8, (u16*)Bs + ch * 8);
    }
    __syncthreads();
    bf16x8 af[4], bfr[4];
#pragma unroll
    for (int mi = 0; mi < 4; ++mi)
      af[mi] = *(const bf16x8*)&As[wr * 64 + mi * 16 + lr][cA * 8];
#pragma unroll
    for (int nj = 0; nj < 4; ++nj)
      bfr[nj] = *(const bf16x8*)&Bs[wc * 64 + nj * 16 + lr][cA * 8];
#pragma unroll
    for (int mi = 0; mi < 4; ++mi)
#pragma unroll
      for (int nj = 0; nj < 4; ++nj)
        acc[mi][nj] = mfma16(af[mi], bfr[nj], acc[mi][nj]);
    __syncthreads();
  }

#pragma unroll
  for (int mi = 0; mi < 4; ++mi)
#pragma unroll
    for (int nj = 0; nj < 4; ++nj) {
      const int i0 = m0 + wr * 64 + mi * 16 + lg * 4;
      const int j  = n0 + wc * 64 + nj * 16 + lr;
      const float4 bp = *(const float4*)(bias + i0);
      float4 o;
      o.x = acc[mi][nj][0] + bp.x; o.y = acc[mi][nj][1] + bp.y;
      o.z = acc[mi][nj][2] + bp.z; o.w = acc[mi][nj][3] + bp.w;
      *(float4*)(fout + (size_t)j * 512 + i0) = o;
    }
}

// ---------------- flash attention (32x32 swapped-operand, sigma-PV, LDS table) ----
// grid 256 (1/CU), 1024 thr = 16 waves = 4 heads x 2 q-subtiles x 2 KV-halves.
// Round-20 register shape + exp2 domain with RAW v_exp_f32 via
// __builtin_amdgcn_exp2f (exp2f() libm entry added range-fixup VALU ops - r22).
__global__ __launch_bounds__(1024) void flash_attn(
    const u16* __restrict__ Qs, const u16* __restrict__ Ks,
    const u16* __restrict__ Vs, const int* __restrict__ ids_keep,
    const u16* __restrict__ tab_bf,
    u16* __restrict__ attn_out)
{
  __shared__ union {
    u16 tabL[2][16129 * 2];    // [head-pair][idx*2 + hlow], 4B stride, 129 KB
    float comb[8][33][64];     // epilogue KV-half combine
  } sm;
  __shared__ int bofs[1024];   // (8064 - code[m]) * 4  (byte offset)

  const int bid = blockIdx.x;
  const int bb = bid & 7;
  const int r2 = bid >> 3;
  const int hp = r2 & 1;
  const int g64 = r2 >> 1;
  const int tid = threadIdx.x;
  const int wv = tid >> 6;          // 0..15
  const int hloc = wv & 3;
  const int qs = (wv >> 2) & 1;
  const int kvh = wv >> 3;          // KV half
  const int l = tid & 63, l31 = l & 31, hi5 = l >> 5;
  const int h = hp * 4 + hloc;
  const int t0 = kvh * 8;

  for (int e = tid; e < 16129 * 2; e += 1024) {
    const int hi = e >= 16129;
    const int ee = hi ? e - 16129 : e;
    *(u32*)&sm.tabL[hi][ee * 2] =
        *(const u32*)(tab_bf + (size_t)ee * 8 + hp * 4 + hi * 2);
  }
  {
    const int id = ids_keep[bb * 1024 + tid];
    bofs[tid] = (8064 - ((id >> 6) * 127 + (id & 63))) * 4;
  }

  const int nloc = g64 * 64 + qs * 32 + l31;
  const int idn = ids_keep[bb * 1024 + nloc];
  const int base = ((idn >> 6) * 127 + (idn & 63)) * 4 + (hloc & 1) * 2;  // bytes

  const size_t hb = (size_t)(bb * 8 + h) << 16;
  const int g32 = g64 * 2 + qs;

  f32x16 acc0 = {}, acc1 = {};
  float lsum = 0.f;

  bf16x8 qf[4];
#pragma unroll
  for (int dch = 0; dch < 4; ++dch)
    qf[dch] = *(const bf16x8*)(Qs + hb + (size_t)(((g32 * 4 + dch) * 2 + hi5) * 256 + l31 * 8));

  __syncthreads();   // tabL + bofs ready; main loop barrier-free

  const char* tb = (const char*)sm.tabL[hloc >> 1];

  for (int t = t0; t < t0 + 8; ++t) {
    u32 pk[2][4][2];
#pragma unroll
    for (int u = 0; u < 2; ++u) {
      bf16x8 kc[4];
#pragma unroll
      for (int dch = 0; dch < 4; ++dch)
        kc[dch] = *(const bf16x8*)(Ks + hb +
            (size_t)((((2 * t + u) * 4 + dch) * 2 + hi5) * 256 + l31 * 8));
      f32x16 s = {};
      s = mfma32(kc[0], qf[0], s);
      s = mfma32(kc[1], qf[1], s);
      s = mfma32(kc[2], qf[2], s);
      s = mfma32(kc[3], qf[3], s);
#pragma unroll
      for (int a = 0; a < 4; ++a) {
        // m = 32u + 8a + 4*hi5 + r
        const int4 bo = *(const int4*)&bofs[t * 64 + u * 32 + a * 8 + hi5 * 4];
        const float b0 = bf2f(*(const u16*)(tb + base + bo.x));
        const float b1 = bf2f(*(const u16*)(tb + base + bo.y));
        const float b2 = bf2f(*(const u16*)(tb + base + bo.z));
        const float b3 = bf2f(*(const u16*)(tb + base + bo.w));
        float p0 = __builtin_amdgcn_exp2f(s[a * 4 + 0] + b0);
        float p1 = __builtin_amdgcn_exp2f(s[a * 4 + 1] + b1);
        float p2 = __builtin_amdgcn_exp2f(s[a * 4 + 2] + b2);
        float p3 = __builtin_amdgcn_exp2f(s[a * 4 + 3] + b3);
        lsum += (p0 + p1) + (p2 + p3);
        pk[u][a][0] = pack2(p0, p1);
        pk[u][a][1] = pack2(p2, p3);
      }
    }

#pragma unroll
    for (int cp = 0; cp < 4; ++cp) {
      bf16x8 vc[2];
#pragma unroll
      for (int dc = 0; dc < 2; ++dc)
        vc[dc] = *(const bf16x8*)(Vs + hb +
            (size_t)(((t * 4 + cp) * 2 + hi5) * 512 + (dc * 32 + l31) * 8));
      const int u = cp >> 1, cc = cp & 1;
      union { u32x4 u4; bf16x8 v; } pb;
      pb.u4 = (u32x4){pk[u][2 * cc][0], pk[u][2 * cc][1],
                      pk[u][2 * cc + 1][0], pk[u][2 * cc + 1][1]};
      acc0 = mfma32(vc[0], pb.v, acc0);
      acc1 = mfma32(vc[1], pb.v, acc1);
    }
  }

  lsum += __shfl_xor(lsum, 32);

  // in-block KV-half combine through the (now dead) table LDS
  __syncthreads();
  const int slot = wv & 7;
  if (kvh == 1) {
#pragma unroll
    for (int r = 0; r < 16; ++r) sm.comb[slot][r][l]      = acc0[r];
#pragma unroll
    for (int r = 0; r < 16; ++r) sm.comb[slot][16 + r][l] = acc1[r];
    sm.comb[slot][32][l] = lsum;
  }
  __syncthreads();
  if (kvh == 0) {
    const float inv = 1.0f / (lsum + sm.comb[slot][32][l]);
    const int nglob = bb * 1024 + nloc;
#pragma unroll
    for (int dc = 0; dc < 2; ++dc) {
      const f32x16& av = dc ? acc1 : acc0;
#pragma unroll
      for (int rq = 0; rq < 4; ++rq) {
        const int d = dc * 32 + rq * 8 + hi5 * 4;
        ushort4 o;
        o.x = f2bf((av[rq * 4 + 0] + sm.comb[slot][dc * 16 + rq * 4 + 0][l]) * inv);
        o.y = f2bf((av[rq * 4 + 1] + sm.comb[slot][dc * 16 + rq * 4 + 1][l]) * inv);
        o.z = f2bf((av[rq * 4 + 2] + sm.comb[slot][dc * 16 + rq * 4 + 2][l]) * inv);
        o.w = f2bf((av[rq * 4 + 3] + sm.comb[slot][dc * 16 + rq * 4 + 3][l]) * inv);
        *(ushort4*)(attn_out + (size_t)nglob * 512 + h * 64 + d) = o;
      }
    }
  }
}

// ---------------- launch ----------------
extern "C" void kernel_launch(void* const* d_in, const int* in_sizes, int n_in,
                              void* d_out, int out_size, void* d_ws, size_t ws_size,
                              hipStream_t stream) {
  const float* x        = (const float*)d_in[0];
  const int*   ids      = (const int*)d_in[1];
  const float* w_qkv    = (const float*)d_in[2];
  const float* w_proj   = (const float*)d_in[3];
  const float* b_proj   = (const float*)d_in[4];
  const float* rel_tab  = (const float*)d_in[5];
  float* out = (float*)d_out;

  char* ws = (char*)d_ws;
  u16* xb   = (u16*)(ws);              // 8192x512 bf16; later reused as attn_out
  u16* wT   = (u16*)(ws + 8388608);    // 1536x512 bf16
  u16* wpT  = (u16*)(ws + 9961472);    // 512x512 bf16
  u16* Qsw  = (u16*)(ws + 10485760);   // swizzled Q, pre-scaled 0.125*log2e (8MB)
  u16* Ksw  = (u16*)(ws + 18874368);   // swizzled K (8MB)
  u16* Vsw  = (u16*)(ws + 27262976);   // sigma-swizzled V (8MB)
  u16* tabb = (u16*)(ws + 35651584);   // bf16 rel_table*log2e [16131][8] (258KB)
  u16* attn = xb;

  prep_all<<<5247, 256, 0, stream>>>(x, w_qkv, w_proj, rel_tab, xb, wT, wpT, tabb);
  gemm_qkv<<<768, 256, 0, stream>>>(xb, wT, Qsw, Ksw, Vsw);
  flash_attn<<<dim3(256), 1024, 0, stream>>>(Qsw, Ksw, Vsw, ids, tabb, attn);
  gemm_proj<<<dim3(64, 4), 256, 0, stream>>>(wpT, attn, out, b_proj);
}